// Round 18
// baseline (109.911 us; speedup 1.0000x reference)
//
#include <hip/hip_runtime.h>

typedef unsigned short u16;
typedef unsigned int u32;
typedef short bf16x8 __attribute__((ext_vector_type(8)));
typedef float f32x4 __attribute__((ext_vector_type(4)));
typedef float f32x16 __attribute__((ext_vector_type(16)));

#define MFMA(a, b, c) __builtin_amdgcn_mfma_f32_16x16x32_bf16(a, b, c, 0, 0, 0)
#define MFMA32(a, b, c) __builtin_amdgcn_mfma_f32_32x32x16_bf16(a, b, c, 0, 0, 0)

// f32 -> bf16 round-to-nearest-even
__device__ __forceinline__ u16 f2bf(float f) {
  unsigned int u = __float_as_uint(f);
  u = (u + 0x7FFFu + ((u >> 16) & 1u)) >> 16;
  return (u16)u;
}

// async global->LDS, 16B per lane; lds dest must be wave-uniform base (HW adds lane*16)
#define GLOAD16(gp, lp)                                                        \
  __builtin_amdgcn_global_load_lds(                                            \
      (const __attribute__((address_space(1))) void*)(gp),                     \
      (__attribute__((address_space(3))) void*)(lp), 16, 0, 0)

// ---------------- fused prep kernel ----------------
__global__ __launch_bounds__(256) void prep_all(
    const float* __restrict__ x, const float* __restrict__ WQ,
    const float* __restrict__ WK, const float* __restrict__ WV,
    const float* __restrict__ WO, float* __restrict__ cost, float* __restrict__ sint,
    u16* __restrict__ xb, u16* __restrict__ Wt, u16* __restrict__ WoT) {
  __shared__ float tile[32][33];
  const int bid = blockIdx.x, tid = threadIdx.x;

  if (bid < 256) {  // rope tables (2048 x 32)
    int idx = bid * 256 + tid;
    int t = idx >> 5, i = idx & 31;
    float invf = expf(-(float)i * 0.28782313662425572f);
    float ang = (float)t * invf;
    cost[idx] = cosf(ang);
    sint[idx] = sinf(ang);
  } else if (bid < 3328) {  // cast x (4096*768 f32 -> bf16, 4/thread)
    int i = ((bid - 256) * 256 + tid) * 4;
    float4 v = *(const float4*)(x + i);
    ushort4 o = make_ushort4(f2bf(v.x), f2bf(v.y), f2bf(v.z), f2bf(v.w));
    *(ushort4*)(xb + i) = o;
  } else if (bid < 5056) {  // Wqkv transpose: Wt[qkv*768+h*64+d][c] = W[h][c][d]
    const int pbid = bid - 3328;
    const int z = pbid / 48, rem = pbid - z * 48;
    const int y = rem / 24, xk = rem - y * 24;
    const int qkv = z / 12, h = z - qkv * 12;
    const float* W = (qkv == 0 ? WQ : qkv == 1 ? WK : WV) + (size_t)h * 768 * 64;
    const int k0 = xk * 32, d0 = y * 32;
    const int tx = tid & 31, ty = tid >> 5;
#pragma unroll
    for (int it = 0; it < 4; it++)
      tile[ty + it * 8][tx] = W[(size_t)(k0 + ty + it * 8) * 64 + d0 + tx];
    __syncthreads();
    u16* out = Wt + (size_t)(qkv * 768 + h * 64 + d0) * 768 + k0;
#pragma unroll
    for (int it = 0; it < 4; it++)
      out[(size_t)(ty + it * 8) * 768 + tx] = f2bf(tile[tx][ty + it * 8]);
  } else {  // Wo transpose
    const int wbid = bid - 5056;
    const int a0 = (wbid % 24) * 32, m0 = (wbid / 24) * 32;
    const int tx = tid & 31, ty = tid >> 5;
#pragma unroll
    for (int it = 0; it < 4; it++)
      tile[ty + it * 8][tx] = WO[(size_t)(a0 + ty + it * 8) * 768 + m0 + tx];
    __syncthreads();
#pragma unroll
    for (int it = 0; it < 4; it++)
      WoT[(size_t)(m0 + ty + it * 8) * 768 + a0 + tx] = f2bf(tile[tx][ty + it * 8]);
  }
}

// ---------------- QKV GEMM (R16-measured best, unchanged) ----------------
__global__ __launch_bounds__(256) void gemm_qkv(
    const u16* __restrict__ A, const u16* __restrict__ Bt,
    const float* __restrict__ bQ, const float* __restrict__ bK, const float* __restrict__ bV,
    const float* __restrict__ cost, const float* __restrict__ sint,
    u16* __restrict__ Qb, u16* __restrict__ Kb, u16* __restrict__ Vt) {
  __shared__ u16 As[3][128 * 32];
  __shared__ u16 Bs[3][96 * 32];
  const int tid = threadIdx.x;
  const int w = tid >> 6, l = tid & 63;
  const int lr = l >> 4, lc = l & 15;
  const int wr = w >> 1, wc = w & 1;

  const int id = blockIdx.x;
  const int xcd = id & 7, idx = id >> 3;
  const int m0 = (xcd * 4 + (idx & 3)) * 128;
  const int n0 = (idx >> 2) * 96;

  f32x4 acc[4][3];
#pragma unroll
  for (int mi = 0; mi < 4; mi++)
#pragma unroll
    for (int ni = 0; ni < 3; ni++) acc[mi][ni] = (f32x4){0.f, 0.f, 0.f, 0.f};

  const int srow = w * 16 + (l >> 2);
  const int sg = (l & 3) ^ ((l >> 3) & 3);
  const u16* ga = A + (size_t)(m0 + srow) * 768 + sg * 8;
  const u16* gb = Bt + (size_t)(n0 + srow) * 768 + sg * 8;
  const u16* gb2 = Bt + (size_t)(n0 + 64 + w * 16 + (l >> 2)) * 768 + sg * 8;

#define GSTAGE(t, bi)                                                     \
  {                                                                       \
    const int kk = (t) * 32;                                              \
    GLOAD16(ga + kk, &As[bi][w * 512]);                                   \
    GLOAD16(ga + kk + (size_t)64 * 768, &As[bi][2048 + w * 512]);         \
    GLOAD16(gb + kk, &Bs[bi][w * 512]);                                   \
    if (w < 2) GLOAD16(gb2 + kk, &Bs[bi][2048 + w * 512]);                \
  }

  const int nt = 24;
  GSTAGE(0, 0);
  GSTAGE(1, 1);

  for (int kt = 0; kt < nt; kt++) {
    if (kt + 1 < nt) {
      if (w < 2) asm volatile("s_waitcnt vmcnt(4)" ::: "memory");
      else       asm volatile("s_waitcnt vmcnt(3)" ::: "memory");
    } else {
      asm volatile("s_waitcnt vmcnt(0)" ::: "memory");
    }
    __builtin_amdgcn_s_barrier();
    __builtin_amdgcn_sched_barrier(0);
    if (kt + 2 < nt) GSTAGE(kt + 2, (kt + 2) % 3);

    const char* as = (const char*)As[kt % 3];
    const char* bs = (const char*)Bs[kt % 3];
    bf16x8 af[4], bfr[3];
#pragma unroll
    for (int mi = 0; mi < 4; mi++) {
      const int row = wr * 64 + mi * 16 + lc;
      af[mi] = *(const bf16x8*)(as + row * 64 + ((lr ^ ((row >> 1) & 3)) << 4));
    }
#pragma unroll
    for (int ni = 0; ni < 3; ni++) {
      const int row = wc * 48 + ni * 16 + lc;
      bfr[ni] = *(const bf16x8*)(bs + row * 64 + ((lr ^ ((row >> 1) & 3)) << 4));
    }
    __builtin_amdgcn_s_setprio(1);
#pragma unroll
    for (int mi = 0; mi < 4; mi++)
#pragma unroll
      for (int ni = 0; ni < 3; ni++)
        acc[mi][ni] = MFMA(af[mi], bfr[ni], acc[mi][ni]);
    __builtin_amdgcn_s_setprio(0);
  }
#undef GSTAGE

#pragma unroll
  for (int mi = 0; mi < 4; mi++) {
#pragma unroll
    for (int ni = 0; ni < 3; ni++) {
      const int col = n0 + wc * 48 + ni * 16 + lc;
      const int rowb = m0 + wr * 64 + mi * 16 + lr * 4;
      const int qkv = col / 768;
      const int rem = col - qkv * 768;
      const int h = rem >> 6, d = rem & 63, fi = d >> 1;
      const float bb = (qkv == 0 ? bQ : qkv == 1 ? bK : bV)[rem];
#pragma unroll
      for (int r = 0; r < 4; r++) {
        const int grow = rowb + r;
        const int t = grow & 2047;
        float v = acc[mi][ni][r] + bb;
        float pv = __shfl_xor(v, 1);
        if (qkv < 2) {
          const float c = cost[t * 32 + fi], s = sint[t * 32 + fi];
          float o = (d & 1) ? (pv * s + v * c) : (v * c - pv * s);
          if (qkv == 0) o *= 0.125f;
          (qkv == 0 ? Qb : Kb)[(size_t)grow * 768 + rem] = f2bf(o);
        } else {
          const int bidx = grow >> 11;
          Vt[((size_t)(bidx * 12 + h) * 64 + d) * 2048 + t] = f2bf(v);
        }
      }
    }
  }
}

// ---------------- out-proj GEMM (R16, unchanged) ----------------
__global__ __launch_bounds__(256) void gemm_out(
    const u16* __restrict__ A, const u16* __restrict__ Bt,
    const float* __restrict__ bO, float* __restrict__ Out) {
  __shared__ u16 As[3][64 * 32];
  __shared__ u16 Bs[3][96 * 32];
  const int tid = threadIdx.x;
  const int w = tid >> 6, l = tid & 63;
  const int lr = l >> 4, lc = l & 15;
  const int wr = w >> 1, wc = w & 1;

  const int id = blockIdx.x;            // 512 = 8 xcd * (8 m x 8 n)
  const int xcd = id & 7, idx = id >> 3;
  const int m0 = (xcd * 8 + (idx & 7)) * 64;
  const int n0 = (idx >> 3) * 96;

  f32x4 acc[2][3];
#pragma unroll
  for (int mi = 0; mi < 2; mi++)
#pragma unroll
    for (int ni = 0; ni < 3; ni++) acc[mi][ni] = (f32x4){0.f, 0.f, 0.f, 0.f};

  const int srow = w * 16 + (l >> 2);
  const int sg = (l & 3) ^ ((l >> 3) & 3);
  const u16* ga = A + (size_t)(m0 + (srow & 63)) * 768 + sg * 8;
  const u16* gb = Bt + (size_t)(n0 + srow) * 768 + sg * 8;
  const u16* gb2 = Bt + (size_t)(n0 + 64 + w * 16 + (l >> 2)) * 768 + sg * 8;

#define GSTAGE(t, bi)                                                   \
  {                                                                     \
    const int kk = (t) * 32;                                            \
    GLOAD16(ga + kk, &As[bi][w * 512]);                                 \
    GLOAD16(gb + kk, &Bs[bi][w * 512]);                                 \
    if (w < 2) GLOAD16(gb2 + kk, &Bs[bi][2048 + w * 512]);              \
  }

  const int nt = 24;
  GSTAGE(0, 0);
  GSTAGE(1, 1);

  for (int kt = 0; kt < nt; kt++) {
    if (kt + 1 < nt) {
      if (w < 2) asm volatile("s_waitcnt vmcnt(3)" ::: "memory");
      else       asm volatile("s_waitcnt vmcnt(2)" ::: "memory");
    } else {
      asm volatile("s_waitcnt vmcnt(0)" ::: "memory");
    }
    __builtin_amdgcn_s_barrier();
    __builtin_amdgcn_sched_barrier(0);
    if (kt + 2 < nt) GSTAGE(kt + 2, (kt + 2) % 3);

    const char* as = (const char*)As[kt % 3];
    const char* bs = (const char*)Bs[kt % 3];
    bf16x8 af[2], bfr[3];
#pragma unroll
    for (int mi = 0; mi < 2; mi++) {
      const int row = wr * 32 + mi * 16 + lc;
      af[mi] = *(const bf16x8*)(as + row * 64 + ((lr ^ ((row >> 1) & 3)) << 4));
    }
#pragma unroll
    for (int ni = 0; ni < 3; ni++) {
      const int row = wc * 48 + ni * 16 + lc;
      bfr[ni] = *(const bf16x8*)(bs + row * 64 + ((lr ^ ((row >> 1) & 3)) << 4));
    }
    __builtin_amdgcn_s_setprio(1);
#pragma unroll
    for (int mi = 0; mi < 2; mi++)
#pragma unroll
      for (int ni = 0; ni < 3; ni++)
        acc[mi][ni] = MFMA(af[mi], bfr[ni], acc[mi][ni]);
    __builtin_amdgcn_s_setprio(0);
  }
#undef GSTAGE

#pragma unroll
  for (int mi = 0; mi < 2; mi++) {
#pragma unroll
    for (int ni = 0; ni < 3; ni++) {
      const int col = n0 + wc * 48 + ni * 16 + lc;
      const int rowb = m0 + wr * 32 + mi * 16 + lr * 4;
      const float bb = bO[col];
#pragma unroll
      for (int r = 0; r < 4; r++) {
        const int grow = rowb + r;
        Out[(size_t)grow * 768 + col] = acc[mi][ni][r] + bb;
      }
    }
  }
}

// ---------------- causal flash attention: fused q-tile-pair, shared KV stream ----------
// 384 blocks x 4 waves = 2 q-tiles x 2 q-halves. Waves 0,1 own tileL=31-x;
// waves 2,3 own tileS=x. tileS's kv range [0,x] is a SUBSET of tileL's
// [0,31-x], so ONE staged K/V stream serves both tiles (staging traffic -50%
// vs R16's sequential halves; block-iterations 12672 -> 9408). Waves 2,3
// predicate off compute after their diagonal but keep staging + barriers.
// 3 buffers, prefetch depth 2, counted vmcnt(4) (4 stage-instr/wave/tile).
// Per-wave math identical to the R16-verified kernel. LDS 48KB.
__global__ __launch_bounds__(256) void attn_kernel(
    const u16* __restrict__ Qb, const u16* __restrict__ Kb,
    const u16* __restrict__ Vt, u16* __restrict__ Ob) {
  __shared__ char Kls[3][8192];   // [buf][64 key rows][128B d]
  __shared__ char Vls[3][8192];   // [buf][64 d rows][128B keys]

  const int id = blockIdx.x;               // 384 = 8 xcd * 48
  const int s_ = id >> 3;
  const int bh = (id & 7) + 8 * (s_ % 3);  // same-bh blocks share an XCD
  const int x = s_ / 3;                    // 0..15
  const int b = bh / 12, h = bh - b * 12;
  const int tid = threadIdx.x, w = tid >> 6, l = tid & 63;
  const int lq = l & 31, hi = l >> 5;
  const int qhalf = w & 1;
  const int qtile = (w >> 1) ? x : 31 - x; // waves 0,1: tileL; waves 2,3: tileS
  const int myN = qtile + 1;               // kv tiles this wave computes
  const int n = 32 - x;                    // kv tiles staged (tileL's range)

  const u16* kbase = Kb + (size_t)(b * 2048) * 768 + h * 64;
  const u16* vbase = Vt + (size_t)(bh * 64) * 2048;

  // staging: wave w covers rows [16w,16w+16) of K and V; pre-swizzled col
  const int r8 = l >> 3;
  const int scol8 = (l & 7) ^ r8;
  const u16* ksrc = kbase + (size_t)(w * 16 + r8) * 768 + scol8 * 8;
  const u16* vsrc = vbase + (size_t)(w * 16 + r8) * 2048 + scol8 * 8;

#define STAGE(t, bi)                                                        \
  {                                                                         \
    const size_t ko = (size_t)(t) * 64 * 768;                               \
    const int vo = (t) * 64;                                                \
    GLOAD16(ksrc + ko,            &Kls[bi][w * 2048]);                      \
    GLOAD16(ksrc + ko + 8 * 768,  &Kls[bi][w * 2048 + 1024]);               \
    GLOAD16(vsrc + vo,            &Vls[bi][w * 2048]);                      \
    GLOAD16(vsrc + vo + 8 * 2048, &Vls[bi][w * 2048 + 1024]);               \
  }

  const int fswz = (lq & 7) << 4;  // fragment-read XOR swizzle

  // Q fragments: lane holds col=q=(qtile*64 + qhalf*32 + lq), k(d)=c*16+hi*8+j
  bf16x8 qf[4];
  {
    const u16* qp = Qb + ((size_t)(b * 2048 + qtile * 64 + qhalf * 32 + lq)) * 768 +
                    h * 64 + hi * 8;
#pragma unroll
    for (int c = 0; c < 4; c++) qf[c] = *(const bf16x8*)(qp + c * 16);
  }

  float m_run = -INFINITY, l_run = 0.f;
  f32x16 acc2[2];
  acc2[0] = (f32x16)0.0f;
  acc2[1] = (f32x16)0.0f;

  STAGE(0, 0);
  if (n > 1) STAGE(1, 1);

  for (int kv = 0; kv < n; kv++) {
    if (kv + 1 < n) asm volatile("s_waitcnt vmcnt(4)" ::: "memory");
    else            asm volatile("s_waitcnt vmcnt(0)" ::: "memory");
    __builtin_amdgcn_s_barrier();
    __builtin_amdgcn_sched_barrier(0);
    if (kv + 2 < n) STAGE(kv + 2, (kv + 2) % 3);

    if (kv < myN) {
      const int cur = kv % 3;
      const char* kls = Kls[cur];
      const char* vls = Vls[cur];

      f32x16 s2[2];
      s2[0] = (f32x16)0.0f;
      s2[1] = (f32x16)0.0f;
      __builtin_amdgcn_s_setprio(1);
#pragma unroll
      for (int c = 0; c < 4; c++) {
        const int cb = (c * 32 + hi * 16) ^ fswz;
        bf16x8 kf0 = *(const bf16x8*)(kls + lq * 128 + cb);
        bf16x8 kf1 = *(const bf16x8*)(kls + (32 + lq) * 128 + cb);
        s2[0] = MFMA32(kf0, qf[c], s2[0]);
        s2[1] = MFMA32(kf1, qf[c], s2[1]);
      }
      __builtin_amdgcn_s_setprio(0);

      if (kv == qtile) {  // causal mask inside diagonal tile
        const int qrel = qhalf * 32 + lq;
#pragma unroll
        for (int kt2 = 0; kt2 < 2; kt2++)
#pragma unroll
          for (int r = 0; r < 16; r++) {
            const int ko = kt2 * 32 + (r & 3) + 8 * (r >> 2) + 4 * hi;
            if (ko > qrel) s2[kt2][r] = -INFINITY;
          }
      }

      float pm = s2[0][0];
#pragma unroll
      for (int r = 1; r < 16; r++) pm = fmaxf(pm, s2[0][r]);
#pragma unroll
      for (int r = 0; r < 16; r++) pm = fmaxf(pm, s2[1][r]);
      pm = fmaxf(pm, __shfl_xor(pm, 32));

      // defer-max (T13, THR=8): first iteration m_run=-inf -> normal path
      const bool defer = __all(pm <= m_run + 8.0f);
      if (!defer) {
        const float mn = fmaxf(m_run, pm);
        const float alpha = __expf(m_run - mn);
        m_run = mn;
        l_run *= alpha;
#pragma unroll
        for (int dh = 0; dh < 2; dh++)
#pragma unroll
          for (int r = 0; r < 16; r++) acc2[dh][r] *= alpha;
      }

      float rs = 0.f;
      u32 pk[2][8];
#pragma unroll
      for (int kt2 = 0; kt2 < 2; kt2++)
#pragma unroll
        for (int j = 0; j < 8; j++) {
          float p0 = __expf(s2[kt2][2 * j] - m_run);
          float p1 = __expf(s2[kt2][2 * j + 1] - m_run);
          rs += p0 + p1;
          asm("v_cvt_pk_bf16_f32 %0, %1, %2" : "=v"(pk[kt2][j]) : "v"(p0), "v"(p1));
        }
      l_run += rs;

      union { u32 u[4]; bf16x8 v; } pf[4];
#pragma unroll
      for (int kq = 0; kq < 4; kq++) {
        const int kt2 = kq >> 1, i0 = 4 * (kq & 1);
        u32 a0 = pk[kt2][i0], b0 = pk[kt2][i0 + 2];
        u32 a1 = pk[kt2][i0 + 1], b1 = pk[kt2][i0 + 3];
        asm("v_permlane32_swap_b32 %0, %1" : "+v"(a0), "+v"(b0));
        asm("v_permlane32_swap_b32 %0, %1" : "+v"(a1), "+v"(b1));
        pf[kq].u[0] = a0; pf[kq].u[1] = a1; pf[kq].u[2] = b0; pf[kq].u[3] = b1;
      }

      __builtin_amdgcn_s_setprio(1);
#pragma unroll
      for (int dh = 0; dh < 2; dh++) {
        const char* vr = vls + (dh * 32 + lq) * 128;
#pragma unroll
        for (int kq = 0; kq < 4; kq++) {
          bf16x8 vf = *(const bf16x8*)(vr + ((kq * 32 + hi * 16) ^ fswz));
          acc2[dh] = MFMA32(vf, pf[kq].v, acc2[dh]);
        }
      }
      __builtin_amdgcn_s_setprio(0);
    }
  }
#undef STAGE

  // epilogue: direct normalized write (each wave owns distinct q rows)
  const float lt = l_run + __shfl_xor(l_run, 32);
  const float inv = 1.0f / lt;
  u16* ob = Ob + ((size_t)(b * 2048 + qtile * 64 + qhalf * 32 + lq)) * 768 + h * 64;
#pragma unroll
  for (int dh = 0; dh < 2; dh++)
#pragma unroll
    for (int g = 0; g < 4; g++) {
      ushort4 o4;
      o4.x = f2bf(acc2[dh][4 * g + 0] * inv);
      o4.y = f2bf(acc2[dh][4 * g + 1] * inv);
      o4.z = f2bf(acc2[dh][4 * g + 2] * inv);
      o4.w = f2bf(acc2[dh][4 * g + 3] * inv);
      *(ushort4*)(ob + dh * 32 + 8 * g + 4 * hi) = o4;
    }
}

// ---------------- launcher ----------------

extern "C" void kernel_launch(void* const* d_in, const int* in_sizes, int n_in,
                              void* d_out, int out_size, void* d_ws, size_t ws_size,
                              hipStream_t stream) {
  const float* x  = (const float*)d_in[0];
  const float* WQ = (const float*)d_in[1];
  const float* bQ = (const float*)d_in[2];
  const float* WK = (const float*)d_in[3];
  const float* bK = (const float*)d_in[4];
  const float* WV = (const float*)d_in[5];
  const float* bV = (const float*)d_in[6];
  const float* WO = (const float*)d_in[7];
  const float* bO = (const float*)d_in[8];

  char* ws = (char*)d_ws;
  u16* Xb    = (u16*)(ws + 0);          // 4096x768 bf16
  u16* Wqkv  = (u16*)(ws + 6291456);    // 2304x768 bf16 (B^T)
  u16* WoT   = (u16*)(ws + 9830400);    // 768x768 bf16 (B^T)
  u16* Qb    = (u16*)(ws + 11010048);   // [B][T][768] bf16
  u16* Kb    = (u16*)(ws + 17301504);   // [B][T][768] bf16
  u16* Vt    = (u16*)(ws + 23592960);   // [bh][64][2048] bf16
  u16* Ob    = (u16*)(ws + 29884416);   // [B*T][768] bf16
  float* cost = (float*)(ws + 36175872); // [2048][32]
  float* sint = (float*)(ws + 36438016); // [2048][32]

  prep_all<<<5632, 256, 0, stream>>>(x, WQ, WK, WV, WO, cost, sint, Xb, Wqkv, WoT);

  gemm_qkv<<<768, 256, 0, stream>>>(Xb, Wqkv, bQ, bK, bV, cost, sint, Qb, Kb, Vt);
  attn_kernel<<<384, 256, 0, stream>>>(Qb, Kb, Vt, Ob);
  gemm_out<<<512, 256, 0, stream>>>(Ob, WoT, bO, (float*)d_out);
}

// Round 19
// 95.780 us; speedup vs baseline: 1.1475x; 1.1475x over previous
//
#include <hip/hip_runtime.h>

typedef unsigned short u16;
typedef unsigned int u32;
typedef short bf16x8 __attribute__((ext_vector_type(8)));
typedef float f32x4 __attribute__((ext_vector_type(4)));
typedef float f32x16 __attribute__((ext_vector_type(16)));

#define MFMA(a, b, c) __builtin_amdgcn_mfma_f32_16x16x32_bf16(a, b, c, 0, 0, 0)
#define MFMA32(a, b, c) __builtin_amdgcn_mfma_f32_32x32x16_bf16(a, b, c, 0, 0, 0)

// f32 -> bf16 round-to-nearest-even
__device__ __forceinline__ u16 f2bf(float f) {
  unsigned int u = __float_as_uint(f);
  u = (u + 0x7FFFu + ((u >> 16) & 1u)) >> 16;
  return (u16)u;
}

// async global->LDS, 16B per lane; lds dest must be wave-uniform base (HW adds lane*16)
#define GLOAD16(gp, lp)                                                        \
  __builtin_amdgcn_global_load_lds(                                            \
      (const __attribute__((address_space(1))) void*)(gp),                     \
      (__attribute__((address_space(3))) void*)(lp), 16, 0, 0)

// ---------------- fused prep kernel ----------------
// block ranges: [0,256) rope tables | [256,3328) cast x | [3328,5056) Wqkv^T | [5056,5632) Wo^T
__global__ __launch_bounds__(256) void prep_all(
    const float* __restrict__ x, const float* __restrict__ WQ,
    const float* __restrict__ WK, const float* __restrict__ WV,
    const float* __restrict__ WO, float* __restrict__ cost, float* __restrict__ sint,
    u16* __restrict__ xb, u16* __restrict__ Wt, u16* __restrict__ WoT) {
  __shared__ float tile[32][33];
  const int bid = blockIdx.x, tid = threadIdx.x;

  if (bid < 256) {  // rope tables (2048 x 32)
    int idx = bid * 256 + tid;
    int t = idx >> 5, i = idx & 31;
    float invf = expf(-(float)i * 0.28782313662425572f);
    float ang = (float)t * invf;
    cost[idx] = cosf(ang);
    sint[idx] = sinf(ang);
  } else if (bid < 3328) {  // cast x (4096*768 f32 -> bf16, 4/thread)
    int i = ((bid - 256) * 256 + tid) * 4;
    float4 v = *(const float4*)(x + i);
    ushort4 o = make_ushort4(f2bf(v.x), f2bf(v.y), f2bf(v.z), f2bf(v.w));
    *(ushort4*)(xb + i) = o;
  } else if (bid < 5056) {  // Wqkv transpose: Wt[qkv*768+h*64+d][c] = W[h][c][d]
    const int pbid = bid - 3328;                  // 0..1727
    const int z = pbid / 48, rem = pbid - z * 48; // z 0..35
    const int y = rem / 24, xk = rem - y * 24;    // y 0..1, xk 0..23
    const int qkv = z / 12, h = z - qkv * 12;
    const float* W = (qkv == 0 ? WQ : qkv == 1 ? WK : WV) + (size_t)h * 768 * 64;
    const int k0 = xk * 32, d0 = y * 32;
    const int tx = tid & 31, ty = tid >> 5;
#pragma unroll
    for (int it = 0; it < 4; it++)
      tile[ty + it * 8][tx] = W[(size_t)(k0 + ty + it * 8) * 64 + d0 + tx];
    __syncthreads();
    u16* out = Wt + (size_t)(qkv * 768 + h * 64 + d0) * 768 + k0;
#pragma unroll
    for (int it = 0; it < 4; it++)
      out[(size_t)(ty + it * 8) * 768 + tx] = f2bf(tile[tx][ty + it * 8]);
  } else {  // Wo transpose: WoT[m][hd] = WO[hd][m]
    const int wbid = bid - 5056;  // 0..575
    const int a0 = (wbid % 24) * 32, m0 = (wbid / 24) * 32;
    const int tx = tid & 31, ty = tid >> 5;
#pragma unroll
    for (int it = 0; it < 4; it++)
      tile[ty + it * 8][tx] = WO[(size_t)(a0 + ty + it * 8) * 768 + m0 + tx];
    __syncthreads();
#pragma unroll
    for (int it = 0; it < 4; it++)
      WoT[(size_t)(m0 + ty + it * 8) * 768 + a0 + tx] = f2bf(tile[tx][ty + it * 8]);
  }
}

// ---------------- QKV GEMM: R8 schedule, 128x96 tile, 768 blocks (3/CU exact) ----------
// Measured best across 7 structural variants. 3 LDS bufs, depth-2 prefetch,
// one s_barrier + counted vmcnt/iter, conflict-free swizzle, XCD m-chunking.
// B rows 64-95 staged only by waves 0,1 (vmcnt 4/3 by wave).
__global__ __launch_bounds__(256) void gemm_qkv(
    const u16* __restrict__ A, const u16* __restrict__ Bt,
    const float* __restrict__ bQ, const float* __restrict__ bK, const float* __restrict__ bV,
    const float* __restrict__ cost, const float* __restrict__ sint,
    u16* __restrict__ Qb, u16* __restrict__ Kb, u16* __restrict__ Vt) {
  __shared__ u16 As[3][128 * 32];   // 8KB/buf
  __shared__ u16 Bs[3][96 * 32];    // 6KB/buf  (42KB total -> 3 blocks/CU)
  const int tid = threadIdx.x;
  const int w = tid >> 6, l = tid & 63;
  const int lr = l >> 4, lc = l & 15;
  const int wr = w >> 1, wc = w & 1;

  const int id = blockIdx.x;
  const int xcd = id & 7, idx = id >> 3;
  const int m0 = (xcd * 4 + (idx & 3)) * 128;
  const int n0 = (idx >> 2) * 96;

  f32x4 acc[4][3];
#pragma unroll
  for (int mi = 0; mi < 4; mi++)
#pragma unroll
    for (int ni = 0; ni < 3; ni++) acc[mi][ni] = (f32x4){0.f, 0.f, 0.f, 0.f};

  const int srow = w * 16 + (l >> 2);
  const int sg = (l & 3) ^ ((l >> 3) & 3);
  const u16* ga = A + (size_t)(m0 + srow) * 768 + sg * 8;
  const u16* gb = Bt + (size_t)(n0 + srow) * 768 + sg * 8;
  const u16* gb2 = Bt + (size_t)(n0 + 64 + w * 16 + (l >> 2)) * 768 + sg * 8;

#define GSTAGE(t, bi)                                                     \
  {                                                                       \
    const int kk = (t) * 32;                                              \
    GLOAD16(ga + kk, &As[bi][w * 512]);                                   \
    GLOAD16(ga + kk + (size_t)64 * 768, &As[bi][2048 + w * 512]);         \
    GLOAD16(gb + kk, &Bs[bi][w * 512]);                                   \
    if (w < 2) GLOAD16(gb2 + kk, &Bs[bi][2048 + w * 512]);                \
  }

  const int nt = 24;
  GSTAGE(0, 0);
  GSTAGE(1, 1);

  for (int kt = 0; kt < nt; kt++) {
    if (kt + 1 < nt) {
      if (w < 2) asm volatile("s_waitcnt vmcnt(4)" ::: "memory");
      else       asm volatile("s_waitcnt vmcnt(3)" ::: "memory");
    } else {
      asm volatile("s_waitcnt vmcnt(0)" ::: "memory");
    }
    __builtin_amdgcn_s_barrier();
    __builtin_amdgcn_sched_barrier(0);
    if (kt + 2 < nt) GSTAGE(kt + 2, (kt + 2) % 3);

    const char* as = (const char*)As[kt % 3];
    const char* bs = (const char*)Bs[kt % 3];
    bf16x8 af[4], bfr[3];
#pragma unroll
    for (int mi = 0; mi < 4; mi++) {
      const int row = wr * 64 + mi * 16 + lc;
      af[mi] = *(const bf16x8*)(as + row * 64 + ((lr ^ ((row >> 1) & 3)) << 4));
    }
#pragma unroll
    for (int ni = 0; ni < 3; ni++) {
      const int row = wc * 48 + ni * 16 + lc;
      bfr[ni] = *(const bf16x8*)(bs + row * 64 + ((lr ^ ((row >> 1) & 3)) << 4));
    }
    __builtin_amdgcn_s_setprio(1);
#pragma unroll
    for (int mi = 0; mi < 4; mi++)
#pragma unroll
      for (int ni = 0; ni < 3; ni++)
        acc[mi][ni] = MFMA(af[mi], bfr[ni], acc[mi][ni]);
    __builtin_amdgcn_s_setprio(0);
    // no trailing barrier: next iteration's vmcnt+barrier fences buffer reuse
  }
#undef GSTAGE

  // epilogue: bias + RoPE (Q scaled 1/8) + V scattered to Vt[bh][d][t]
#pragma unroll
  for (int mi = 0; mi < 4; mi++) {
#pragma unroll
    for (int ni = 0; ni < 3; ni++) {
      const int col = n0 + wc * 48 + ni * 16 + lc;
      const int rowb = m0 + wr * 64 + mi * 16 + lr * 4;
      const int qkv = col / 768;  // uniform per fragment (fragment base is 16-aligned)
      const int rem = col - qkv * 768;
      const int h = rem >> 6, d = rem & 63, fi = d >> 1;
      const float bb = (qkv == 0 ? bQ : qkv == 1 ? bK : bV)[rem];
#pragma unroll
      for (int r = 0; r < 4; r++) {
        const int grow = rowb + r;
        const int t = grow & 2047;
        float v = acc[mi][ni][r] + bb;
        float pv = __shfl_xor(v, 1);  // partner of the rope pair (adjacent col)
        if (qkv < 2) {
          const float c = cost[t * 32 + fi], s = sint[t * 32 + fi];
          float o = (d & 1) ? (pv * s + v * c) : (v * c - pv * s);
          if (qkv == 0) o *= 0.125f;  // fold 1/sqrt(64) into Q
          (qkv == 0 ? Qb : Kb)[(size_t)grow * 768 + rem] = f2bf(o);
        } else {
          const int bidx = grow >> 11;
          Vt[((size_t)(bidx * 12 + h) * 64 + d) * 2048 + t] = f2bf(v);
        }
      }
    }
  }
}

// ---------------- out-proj GEMM: 64x96 tile, 512 blocks (2/CU exact) ----------
__global__ __launch_bounds__(256) void gemm_out(
    const u16* __restrict__ A, const u16* __restrict__ Bt,
    const float* __restrict__ bO, float* __restrict__ Out) {
  __shared__ u16 As[3][64 * 32];    // 4KB/buf
  __shared__ u16 Bs[3][96 * 32];    // 6KB/buf (30KB total)
  const int tid = threadIdx.x;
  const int w = tid >> 6, l = tid & 63;
  const int lr = l >> 4, lc = l & 15;
  const int wr = w >> 1, wc = w & 1;

  const int id = blockIdx.x;            // 512 = 8 xcd * (8 m x 8 n)
  const int xcd = id & 7, idx = id >> 3;
  const int m0 = (xcd * 8 + (idx & 7)) * 64;
  const int n0 = (idx >> 3) * 96;

  f32x4 acc[2][3];
#pragma unroll
  for (int mi = 0; mi < 2; mi++)
#pragma unroll
    for (int ni = 0; ni < 3; ni++) acc[mi][ni] = (f32x4){0.f, 0.f, 0.f, 0.f};

  const int srow = w * 16 + (l >> 2);
  const int sg = (l & 3) ^ ((l >> 3) & 3);
  const u16* ga = A + (size_t)(m0 + (srow & 63)) * 768 + sg * 8;  // 64 A rows
  const u16* gb = Bt + (size_t)(n0 + srow) * 768 + sg * 8;        // B rows 0-63
  const u16* gb2 = Bt + (size_t)(n0 + 64 + w * 16 + (l >> 2)) * 768 + sg * 8;

#define GSTAGE(t, bi)                                                   \
  {                                                                     \
    const int kk = (t) * 32;                                            \
    GLOAD16(ga + kk, &As[bi][w * 512]);                                 \
    GLOAD16(gb + kk, &Bs[bi][w * 512]);                                 \
    if (w < 2) GLOAD16(gb2 + kk, &Bs[bi][2048 + w * 512]);              \
  }

  const int nt = 24;
  GSTAGE(0, 0);
  GSTAGE(1, 1);

  for (int kt = 0; kt < nt; kt++) {
    if (kt + 1 < nt) {
      if (w < 2) asm volatile("s_waitcnt vmcnt(3)" ::: "memory");
      else       asm volatile("s_waitcnt vmcnt(2)" ::: "memory");
    } else {
      asm volatile("s_waitcnt vmcnt(0)" ::: "memory");
    }
    __builtin_amdgcn_s_barrier();
    __builtin_amdgcn_sched_barrier(0);
    if (kt + 2 < nt) GSTAGE(kt + 2, (kt + 2) % 3);

    const char* as = (const char*)As[kt % 3];
    const char* bs = (const char*)Bs[kt % 3];
    bf16x8 af[2], bfr[3];
#pragma unroll
    for (int mi = 0; mi < 2; mi++) {
      const int row = wr * 32 + mi * 16 + lc;
      af[mi] = *(const bf16x8*)(as + row * 64 + ((lr ^ ((row >> 1) & 3)) << 4));
    }
#pragma unroll
    for (int ni = 0; ni < 3; ni++) {
      const int row = wc * 48 + ni * 16 + lc;
      bfr[ni] = *(const bf16x8*)(bs + row * 64 + ((lr ^ ((row >> 1) & 3)) << 4));
    }
    __builtin_amdgcn_s_setprio(1);
#pragma unroll
    for (int mi = 0; mi < 2; mi++)
#pragma unroll
      for (int ni = 0; ni < 3; ni++)
        acc[mi][ni] = MFMA(af[mi], bfr[ni], acc[mi][ni]);
    __builtin_amdgcn_s_setprio(0);
  }
#undef GSTAGE

#pragma unroll
  for (int mi = 0; mi < 2; mi++) {
#pragma unroll
    for (int ni = 0; ni < 3; ni++) {
      const int col = n0 + wc * 48 + ni * 16 + lc;
      const int rowb = m0 + wr * 32 + mi * 16 + lr * 4;
      const float bb = bO[col];
#pragma unroll
      for (int r = 0; r < 4; r++) {
        const int grow = rowb + r;
        Out[(size_t)grow * 768 + col] = acc[mi][ni][r] + bb;
      }
    }
  }
}

// ---------------- causal flash attention (R16-measured best, unchanged) ----------------
// 384 blocks x 4 waves = 2 q-halves x 2 kv-parity groups; paired q-tiles
// (31-x then x) = 33 uniform iterations; 4-buffer staging, in-register
// softmax (swapped QK^T), cvt_pk+permlane P, defer-max T13, group merge.
__global__ __launch_bounds__(256, 2) void attn_kernel(
    const u16* __restrict__ Qb, const u16* __restrict__ Kb,
    const u16* __restrict__ Vt, u16* __restrict__ Ob) {
  __shared__ char Kls[4][8192];   // [buf][64 key rows][128B d]
  __shared__ char Vls[4][8192];   // [buf][64 d rows][128B keys]
  char* scratch = (char*)Kls;     // merge scratch (barrier-ordered reuse)

  const int id = blockIdx.x + 16 * blockIdx.y;
  const int s_ = id >> 3;
  const int bh = (id & 7) + 8 * (s_ % 3);  // same-bh blocks share an XCD
  const int xq = s_ / 3;                   // 0..15
  const int b = bh / 12, h = bh - b * 12;
  const int tid = threadIdx.x, w = tid >> 6, l = tid & 63;
  const int lq = l & 31, hi = l >> 5;
  const int qhalf = w & 1, grp = w >> 1;

  const u16* kbase = Kb + (size_t)(b * 2048) * 768 + h * 64;
  const u16* vbase = Vt + (size_t)(bh * 64) * 2048;

  const int r8 = l >> 3;
  const int scol8 = (l & 7) ^ r8;
  const u16* ksrc = kbase + (size_t)(w * 16 + r8) * 768 + scol8 * 8;
  const u16* vsrc = vbase + (size_t)(w * 16 + r8) * 2048 + scol8 * 8;

#define STAGE(t, bi)                                                        \
  {                                                                         \
    const size_t ko = (size_t)(t) * 64 * 768;                               \
    const int vo = (t) * 64;                                                \
    GLOAD16(ksrc + ko,            &Kls[bi][w * 2048]);                      \
    GLOAD16(ksrc + ko + 8 * 768,  &Kls[bi][w * 2048 + 1024]);               \
    GLOAD16(vsrc + vo,            &Vls[bi][w * 2048]);                      \
    GLOAD16(vsrc + vo + 8 * 2048, &Vls[bi][w * 2048 + 1024]);               \
  }

  const int fswz = (lq & 7) << 4;  // fragment-read XOR swizzle

#pragma unroll 1
  for (int half = 0; half < 2; half++) {
    const int qblk = half == 0 ? 31 - xq : xq;
    const int n = qblk + 1;          // kv tiles this phase
    const int nsup = (n + 1) >> 1;   // super-iterations

    bf16x8 qf[4];
    {
      const u16* qp = Qb + ((size_t)(b * 2048 + qblk * 64 + qhalf * 32 + lq)) * 768 +
                      h * 64 + hi * 8;
#pragma unroll
      for (int c = 0; c < 4; c++) qf[c] = *(const bf16x8*)(qp + c * 16);
    }

    float m_run = -INFINITY, l_run = 0.f;
    f32x16 acc2[2];
    acc2[0] = (f32x16)0.0f;
    acc2[1] = (f32x16)0.0f;

    STAGE(0, 0);
    if (n > 1) STAGE(1, 1);

    for (int p = 0; p < nsup; p++) {
      const int t0 = 2 * p;
      asm volatile("s_waitcnt vmcnt(0)" ::: "memory");  // tiles t0, t0+1 landed
      __builtin_amdgcn_s_barrier();
      __builtin_amdgcn_sched_barrier(0);
      if (t0 + 2 < n) STAGE(t0 + 2, (t0 + 2) & 3);
      if (t0 + 3 < n) STAGE(t0 + 3, (t0 + 3) & 3);

      const int tile = t0 + grp;
      if (tile < n) {
        const int cur = tile & 3;

        f32x16 s2[2];
        s2[0] = (f32x16)0.0f;
        s2[1] = (f32x16)0.0f;
        __builtin_amdgcn_s_setprio(1);
#pragma unroll
        for (int c = 0; c < 4; c++) {
          const int cb = (c * 32 + hi * 16) ^ fswz;
          bf16x8 kf0 = *(const bf16x8*)(&Kls[cur][lq * 128] + cb);
          bf16x8 kf1 = *(const bf16x8*)(&Kls[cur][(32 + lq) * 128] + cb);
          s2[0] = MFMA32(kf0, qf[c], s2[0]);
          s2[1] = MFMA32(kf1, qf[c], s2[1]);
        }
        __builtin_amdgcn_s_setprio(0);

        if (tile == qblk) {  // causal mask inside diagonal tile
          const int qrel = qhalf * 32 + lq;
#pragma unroll
          for (int kt2 = 0; kt2 < 2; kt2++)
#pragma unroll
            for (int r = 0; r < 16; r++) {
              const int ko = kt2 * 32 + (r & 3) + 8 * (r >> 2) + 4 * hi;
              if (ko > qrel) s2[kt2][r] = -INFINITY;
            }
        }

        float pm = s2[0][0];
#pragma unroll
        for (int r = 1; r < 16; r++) pm = fmaxf(pm, s2[0][r]);
#pragma unroll
        for (int r = 0; r < 16; r++) pm = fmaxf(pm, s2[1][r]);
        pm = fmaxf(pm, __shfl_xor(pm, 32));

        // defer-max (T13, THR=8): skip rescale when max growth small; P <= e^8.
        const bool defer = __all(pm <= m_run + 8.0f);
        if (!defer) {
          const float mn = fmaxf(m_run, pm);
          const float alpha = __expf(m_run - mn);
          m_run = mn;
          l_run *= alpha;
#pragma unroll
          for (int dh = 0; dh < 2; dh++)
#pragma unroll
            for (int r = 0; r < 16; r++) acc2[dh][r] *= alpha;
        }

        float rs = 0.f;
        u32 pk[2][8];
#pragma unroll
        for (int kt2 = 0; kt2 < 2; kt2++)
#pragma unroll
          for (int j = 0; j < 8; j++) {
            float p0 = __expf(s2[kt2][2 * j] - m_run);
            float p1 = __expf(s2[kt2][2 * j + 1] - m_run);
            rs += p0 + p1;
            asm("v_cvt_pk_bf16_f32 %0, %1, %2" : "=v"(pk[kt2][j]) : "v"(p0), "v"(p1));
          }
        l_run += rs;

        union { u32 u[4]; bf16x8 v; } pf[4];
#pragma unroll
        for (int kq = 0; kq < 4; kq++) {
          const int kt2 = kq >> 1, i0 = 4 * (kq & 1);
          u32 a0 = pk[kt2][i0], b0 = pk[kt2][i0 + 2];
          u32 a1 = pk[kt2][i0 + 1], b1 = pk[kt2][i0 + 3];
          asm("v_permlane32_swap_b32 %0, %1" : "+v"(a0), "+v"(b0));
          asm("v_permlane32_swap_b32 %0, %1" : "+v"(a1), "+v"(b1));
          pf[kq].u[0] = a0; pf[kq].u[1] = a1; pf[kq].u[2] = b0; pf[kq].u[3] = b1;
        }

        __builtin_amdgcn_s_setprio(1);
#pragma unroll
        for (int dh = 0; dh < 2; dh++) {
          const char* vr = &Vls[cur][(dh * 32 + lq) * 128];
#pragma unroll
          for (int kq = 0; kq < 4; kq++) {
            bf16x8 vf = *(const bf16x8*)(vr + ((kq * 32 + hi * 16) ^ fswz));
            acc2[dh] = MFMA32(vf, pf[kq].v, acc2[dh]);
          }
        }
        __builtin_amdgcn_s_setprio(0);
      }
    }

    // ---- merge the two kv-groups via LDS scratch ----
    asm volatile("s_waitcnt lgkmcnt(0)" ::: "memory");
    __builtin_amdgcn_s_barrier();  // A: all compute (and LDS reads) done
    if (grp == 1) {
      float* sc = (float*)scratch + ((size_t)(w - 2) * 64 + l) * 34;
#pragma unroll
      for (int dh = 0; dh < 2; dh++)
#pragma unroll
        for (int r = 0; r < 16; r++) sc[dh * 16 + r] = acc2[dh][r];
      sc[32] = m_run;
      sc[33] = l_run;
    }
    asm volatile("s_waitcnt lgkmcnt(0)" ::: "memory");
    __builtin_amdgcn_s_barrier();  // B: group-1 state visible
    if (grp == 0) {
      const float* sc = (const float*)scratch + ((size_t)w * 64 + l) * 34;
      const float m1 = sc[32], l1 = sc[33];
      const float M = fmaxf(m_run, m1);
      const float a0 = __expf(m_run - M);
      const float a1 = __expf(m1 - M);   // exp(-inf - finite) = 0 when group1 idle
      const float lm = l_run * a0 + l1 * a1;
      const float lt = lm + __shfl_xor(lm, 32);
      const float inv = 1.0f / lt;
      u16* ob = Ob + ((size_t)(b * 2048 + qblk * 64 + qhalf * 32 + lq)) * 768 + h * 64;
#pragma unroll
      for (int dh = 0; dh < 2; dh++)
#pragma unroll
        for (int g = 0; g < 4; g++) {
          ushort4 o4;
          o4.x = f2bf((acc2[dh][4 * g + 0] * a0 + sc[dh * 16 + 4 * g + 0] * a1) * inv);
          o4.y = f2bf((acc2[dh][4 * g + 1] * a0 + sc[dh * 16 + 4 * g + 1] * a1) * inv);
          o4.z = f2bf((acc2[dh][4 * g + 2] * a0 + sc[dh * 16 + 4 * g + 2] * a1) * inv);
          o4.w = f2bf((acc2[dh][4 * g + 3] * a0 + sc[dh * 16 + 4 * g + 3] * a1) * inv);
          *(ushort4*)(ob + dh * 32 + 8 * g + 4 * hi) = o4;
        }
    }
    asm volatile("s_waitcnt lgkmcnt(0)" ::: "memory");
    __builtin_amdgcn_s_barrier();  // C: scratch reads done before next-phase staging
  }
#undef STAGE
}

// ---------------- launcher ----------------

extern "C" void kernel_launch(void* const* d_in, const int* in_sizes, int n_in,
                              void* d_out, int out_size, void* d_ws, size_t ws_size,
                              hipStream_t stream) {
  const float* x  = (const float*)d_in[0];
  const float* WQ = (const float*)d_in[1];
  const float* bQ = (const float*)d_in[2];
  const float* WK = (const float*)d_in[3];
  const float* bK = (const float*)d_in[4];
  const float* WV = (const float*)d_in[5];
  const float* bV = (const float*)d_in[6];
  const float* WO = (const float*)d_in[7];
  const float* bO = (const float*)d_in[8];

  char* ws = (char*)d_ws;
  u16* Xb    = (u16*)(ws + 0);          // 4096x768 bf16
  u16* Wqkv  = (u16*)(ws + 6291456);    // 2304x768 bf16 (B^T)
  u16* WoT   = (u16*)(ws + 9830400);    // 768x768 bf16 (B^T)
  u16* Qb    = (u16*)(ws + 11010048);   // [B][T][768] bf16
  u16* Kb    = (u16*)(ws + 17301504);   // [B][T][768] bf16
  u16* Vt    = (u16*)(ws + 23592960);   // [bh][64][2048] bf16
  u16* Ob    = (u16*)(ws + 29884416);   // [B*T][768] bf16
  float* cost = (float*)(ws + 36175872); // [2048][32]
  float* sint = (float*)(ws + 36438016); // [2048][32]

  prep_all<<<5632, 256, 0, stream>>>(x, WQ, WK, WV, WO, cost, sint, Xb, Wqkv, WoT);

  gemm_qkv<<<768, 256, 0, stream>>>(Xb, Wqkv, bQ, bK, bV, cost, sint, Qb, Kb, Vt);
  attn_kernel<<<dim3(16, 24), 256, 0, stream>>>(Qb, Kb, Vt, Ob);
  gemm_out<<<512, 256, 0, stream>>>(Ob, WoT, bO, (float*)d_out);
}